// Round 1
// baseline (632.088 us; speedup 1.0000x reference)
//
#include <hip/hip_runtime.h>

// Problem constants
#define N_   4
#define M_   4
#define H_   32
#define W_   32
#define HW_  1024
#define K_   4096
#define D_   32
#define TP   8            // positions per block
#define S0   67108864     // N*M*H*W*K
#define NP   16384        // N*M*H*W
#define NEG_INF_ (-1.0e9f)

// --- tiny pre-kernel: code_usage -> expo, stored in ws[0] ---
__global__ __launch_bounds__(256) void usage_kernel(const float* __restrict__ freq,
                                                    float* __restrict__ ws) {
  __shared__ int sc[256];
  int c = 0;
  for (int i = threadIdx.x; i < M_ * K_; i += 256) c += (freq[i] > 1e-7f) ? 1 : 0;
  sc[threadIdx.x] = c;
  __syncthreads();
  for (int s = 128; s > 0; s >>= 1) {
    if (threadIdx.x < s) sc[threadIdx.x] += sc[threadIdx.x + s];
    __syncthreads();
  }
  if (threadIdx.x == 0) {
    float u = (float)sc[0] * (1.0f / 16384.0f);   // exact: count / 2^14
    u = fminf(fmaxf(u, 0.0f), 1.0f);
    float e = 12.0f - 11.0f * (u * u);            // expo = BITS - (BITS-1)*u^2
    ws[0] = e;
  }
}

__device__ __forceinline__ void amax_comb(float& v, int& i, float v2, int i2) {
  // max with first-index (min idx) tie-break — associative & commutative
  if (v2 > v || (v2 == v && i2 < i)) { v = v2; i = i2; }
}

__global__ __launch_bounds__(256) void mcq_kernel(
    const float* __restrict__ x,    // (N, M*D, H, W)
    const float* __restrict__ cb,   // (M, K, D)
    const float* __restrict__ freq, // (M, K)
    const float* __restrict__ temp, // (M)
    const float* __restrict__ dn,   // (N, M, H, W, K)
    const float* __restrict__ gn,   // (N, M, H, W, K)
    const float* __restrict__ ws,
    float* __restrict__ out)
{
  const int tid    = threadIdx.x;
  const int nm     = blockIdx.x >> 7;   // 0..15  (n*M+m)
  const int ptile  = blockIdx.x & 127;  // 0..127
  const int m      = nm & 3;
  const int hw0    = ptile << 3;        // 8 positions
  const int rowbase = (nm << 10) + hw0; // flat position row (n,m,h,w)

  __shared__ float xs[TP][D_];
  __shared__ float x2s[TP];
  {
    const int d = tid >> 3, p = tid & 7;
    // x[n][m*D+d][hw0+p], n = nm>>2
    xs[p][d] = x[((size_t)(nm >> 2) * 128 + (size_t)m * 32 + d) * 1024 + hw0 + p];
  }
  __syncthreads();
  if (tid < TP) {
    float s = 0.f;
    #pragma unroll
    for (int d = 0; d < D_; ++d) s += xs[tid][d] * xs[tid][d];
    x2s[tid] = s;
  }
  __syncthreads();

  const float expo = ws[0];
  const float tlb  = fmaxf(temp[m], 1e-7f);  // lower_bound fwd
  const float* __restrict__ cbm   = cb + (size_t)m * K_ * D_;
  const float* __restrict__ freqm = freq + m * K_;
  float* __restrict__ out_sample = out;
  float* __restrict__ out_code   = out + S0;
  float* __restrict__ out_onehot = out + S0 + NP;
  float* __restrict__ out_logit  = out + (size_t)S0 + NP + S0;

  float lval[TP], gval[TP];
  int   lidx[TP], gidx[TP];
  #pragma unroll
  for (int p = 0; p < TP; ++p) {
    lval[p] = -3.402823466e38f; gval[p] = -3.402823466e38f;
    lidx[p] = 0; gidx[p] = 0;
  }

  for (int kt = 0; kt < K_ / 256; ++kt) {
    const int k = (kt << 8) + tid;
    // codebook row (128 B) into registers; c2 on the fly
    float cr[32];
    float c2 = 0.f;
    const float4* cp = (const float4*)(cbm + (size_t)k * D_);
    #pragma unroll
    for (int j = 0; j < 8; ++j) {
      float4 v = cp[j];
      cr[4*j+0] = v.x; cr[4*j+1] = v.y; cr[4*j+2] = v.z; cr[4*j+3] = v.w;
      c2 += v.x*v.x; c2 += v.y*v.y; c2 += v.z*v.z; c2 += v.w*v.w;
    }
    float dotv[TP];
    #pragma unroll
    for (int p = 0; p < TP; ++p) {
      float a = 0.f;
      #pragma unroll
      for (int d = 0; d < D_; ++d) a = fmaf(cr[d], xs[p][d], a);
      dotv[p] = a;
    }
    const float fv = freqm[k];
    #pragma unroll
    for (int p = 0; p < TP; ++p) {
      const int off = (rowbase + p) * K_ + k;
      const float dnv = __builtin_nontemporal_load(dn + off);
      const float gnv = __builtin_nontemporal_load(gn + off);
      const float dist = (x2s[p] + c2) - 2.0f * dotv[p];
      float lg = dist * (-0.015625f) * tlb;   // (-dist/64)*tlb, /64 exact
      // mask: dn^expo < freq  (exp2/log2; dn=0 -> pv=0, matches 0**e)
      const float pv = exp2f(expo * log2f(dnv));
      if (pv < fv) lg = lg + NEG_INF_;
      __builtin_nontemporal_store(lg, out_logit + off);
      if (lg > lval[p]) { lval[p] = lg; lidx[p] = k; }
      const float lgg = lg + gnv;
      if (lgg > gval[p]) { gval[p] = lgg; gidx[p] = k; }
    }
  }

  // cross-thread argmax reduction: per-wave butterfly, then 4 partials via LDS
  __shared__ float rv[4][16];
  __shared__ int   ri[4][16];
  const int wave = tid >> 6, lane = tid & 63;
  #pragma unroll
  for (int p = 0; p < TP; ++p) {
    float v = lval[p]; int i = lidx[p];
    #pragma unroll
    for (int s = 1; s < 64; s <<= 1) {
      float v2 = __shfl_xor(v, s, 64);
      int   i2 = __shfl_xor(i, s, 64);
      amax_comb(v, i, v2, i2);
    }
    if (lane == 0) { rv[wave][p*2] = v; ri[wave][p*2] = i; }
    v = gval[p]; i = gidx[p];
    #pragma unroll
    for (int s = 1; s < 64; s <<= 1) {
      float v2 = __shfl_xor(v, s, 64);
      int   i2 = __shfl_xor(i, s, 64);
      amax_comb(v, i, v2, i2);
    }
    if (lane == 0) { rv[wave][p*2+1] = v; ri[wave][p*2+1] = i; }
  }
  __syncthreads();
  if (tid < 16) {
    float v = rv[0][tid]; int i = ri[0][tid];
    amax_comb(v, i, rv[1][tid], ri[1][tid]);
    amax_comb(v, i, rv[2][tid], ri[2][tid]);
    amax_comb(v, i, rv[3][tid], ri[3][tid]);
    const int p   = tid >> 1;
    const int row = rowbase + p;
    if ((tid & 1) == 0) {
      // argmax(logit) -> code + one_hot
      out_code[row] = (float)i;
      out_onehot[(size_t)row * K_ + i] = 1.0f;
    } else {
      // argmax(logit + gumbel) -> sample (== y_hard numerically)
      out_sample[(size_t)row * K_ + i] = 1.0f;
    }
  }
}

extern "C" void kernel_launch(void* const* d_in, const int* in_sizes, int n_in,
                              void* d_out, int out_size, void* d_ws, size_t ws_size,
                              hipStream_t stream) {
  const float* x    = (const float*)d_in[0];
  const float* cb   = (const float*)d_in[1];
  const float* freq = (const float*)d_in[2];
  const float* temp = (const float*)d_in[3];
  const float* dn   = (const float*)d_in[4];
  const float* gn   = (const float*)d_in[5];
  float* out = (float*)d_out;
  float* ws  = (float*)d_ws;

  // zero sample + code + one_hot (logit & code fully written by kernel)
  size_t zero_bytes = ((size_t)2 * S0 + NP) * sizeof(float);
  (void)hipMemsetAsync(d_out, 0, zero_bytes, stream);

  usage_kernel<<<1, 256, 0, stream>>>(freq, ws);
  mcq_kernel<<<2048, 256, 0, stream>>>(x, cb, freq, temp, dn, gn, ws, out);
}